// Round 8
// baseline (1558.612 us; speedup 1.0000x reference)
//
#include <hip/hip_runtime.h>
#include <hip/hip_bf16.h>

#define F_DIM   13
#define EDGE_IN 34
#define MSG_DIM 32
#define HID     64
#define NODE_IN 45
#define N_L     20000
#define N_H     100000
#define E_CNT   800000
#define B_CNT   4
#define KTOT    (B_CNT * N_H)      // 400000
#define NE_TOT  (B_CNT * E_CNT)    // 3200000
#define SCAN_N  (KTOT + 1)

#define RS       72                // LDS row stride in halfwords (144 B)
#define GRID_E   2500
#define TPB_T    10                // tiles/block; 2500*10*128 = 3.2M edges

typedef short v8s __attribute__((ext_vector_type(8)));
typedef float v4f __attribute__((ext_vector_type(4)));

// tanh = 1 - 2/(exp2(2log2e*x)+1); rcp(inf)=0 -> saturates to +/-1, no clamps
__device__ __forceinline__ float fast_tanh(float x) {
    float t = __builtin_amdgcn_exp2f(x * 2.885390081777927f);
    return fmaf(-2.f, __builtin_amdgcn_rcpf(t + 1.f), 1.f);
}
__device__ __forceinline__ float fast_sigmoid(float x) {
    float t = __builtin_amdgcn_exp2f(-x * 1.4426950408889634f);
    return __builtin_amdgcn_rcpf(1.f + t);
}
__device__ __forceinline__ short f2bf(float f) {     // round-half-up: 2 instr
    union { float f; unsigned u; } x; x.f = f;
    return (short)((x.u + 0x8000u) >> 16);
}
__device__ __forceinline__ float bf2f(short s) {
    union { unsigned u; float f; } x;
    x.u = ((unsigned)(unsigned short)s) << 16;
    return x.f;
}

// ---------------- CSR build (validated R2-R6) ----------------

__global__ __launch_bounds__(256) void hist_kernel(const int* __restrict__ tgt,
                                                   int* __restrict__ arr) {
    int gid = blockIdx.x * 256 + threadIdx.x;
    int b = gid / E_CNT;
    int t = tgt[gid];
    atomicAdd(&arr[b * N_H + t + 1], 1);
}

__global__ __launch_bounds__(256) void scan_blocks(int* __restrict__ data,
                                                   int* __restrict__ blkSums, int n) {
    __shared__ int sh[256];
    int base = blockIdx.x * 1024 + threadIdx.x * 4;
    int v0 = 0, v1 = 0, v2 = 0, v3 = 0;
    if (base + 0 < n) v0 = data[base + 0];
    if (base + 1 < n) v1 = data[base + 1];
    if (base + 2 < n) v2 = data[base + 2];
    if (base + 3 < n) v3 = data[base + 3];
    v1 += v0; v2 += v1; v3 += v2;
    int val = v3;
    sh[threadIdx.x] = val;
    __syncthreads();
    for (int off = 1; off < 256; off <<= 1) {
        int t = (threadIdx.x >= off) ? sh[threadIdx.x - off] : 0;
        __syncthreads();
        sh[threadIdx.x] += t;
        __syncthreads();
    }
    int excl = sh[threadIdx.x] - val;
    if (base + 0 < n) data[base + 0] = v0 + excl;
    if (base + 1 < n) data[base + 1] = v1 + excl;
    if (base + 2 < n) data[base + 2] = v2 + excl;
    if (base + 3 < n) data[base + 3] = v3 + excl;
    if (threadIdx.x == 255) blkSums[blockIdx.x] = sh[255];
}

__global__ __launch_bounds__(512) void scan_top(const int* __restrict__ blkSums,
                                                int* __restrict__ blkOff, int nb) {
    __shared__ int sh[512];
    int v = (threadIdx.x < nb) ? blkSums[threadIdx.x] : 0;
    sh[threadIdx.x] = v;
    __syncthreads();
    for (int off = 1; off < 512; off <<= 1) {
        int t = (threadIdx.x >= off) ? sh[threadIdx.x - off] : 0;
        __syncthreads();
        sh[threadIdx.x] += t;
        __syncthreads();
    }
    blkOff[threadIdx.x] = sh[threadIdx.x] - v;
}

__global__ __launch_bounds__(256) void scan_add(int* __restrict__ data,
                                                const int* __restrict__ blkOff,
                                                int* __restrict__ cursor, int n, int k) {
    int base = blockIdx.x * 1024 + threadIdx.x * 4;
    int off = blkOff[blockIdx.x];
    #pragma unroll
    for (int j = 0; j < 4; j++) {
        int i = base + j;
        if (i < n) {
            int v = data[i] + off;
            data[i] = v;
            if (i < k) cursor[i] = v;
        }
    }
}

__global__ __launch_bounds__(256) void fill_kernel(const int* __restrict__ tgt,
                                                   int* __restrict__ cursor,
                                                   int* __restrict__ sortedEdge) {
    int gid = blockIdx.x * 256 + threadIdx.x;
    int b = gid / E_CNT;
    int key = b * N_H + tgt[gid];
    int pos = atomicAdd(&cursor[key], 1);
    sortedEdge[pos] = gid;
}

// ---------------- persistent MFMA edge kernel ----------------

__device__ __forceinline__ void load_z(const float* __restrict__ z_l,
                                       const float* __restrict__ z_h,
                                       int b, int s, int t, float* Z) {
    const float* zs = z_l + ((size_t)b * N_L + s) * F_DIM;
    const float* zt = z_h + ((size_t)b * N_H + t) * F_DIM;
    #pragma unroll
    for (int i = 0; i < F_DIM; i++) Z[i] = zs[i];
    #pragma unroll
    for (int i = 0; i < F_DIM; i++) Z[13 + i] = zt[i];
}

__device__ __forceinline__ void write_tile(short* __restrict__ sInp,
                                           int* __restrict__ sKey,
                                           int e_loc, int half,
                                           const float* __restrict__ Z, int key) {
    float d0 = Z[0] - Z[13], d1 = Z[1] - Z[14], d2 = Z[2] - Z[15];
    float dist = d0 * d0 + d1 * d1 + d2 * d2;
    float ax = Z[3], ay = Z[4], az = Z[5];
    float bx = Z[16], by = Z[17], bz = Z[18];
    float cx = ay * bz - az * by;
    float cy = az * bx - ax * bz;
    float cz = ax * by - ay * bx;
    float acr = sqrtf(cx * cx + cy * cy + cz * cz);

    short row[32];
    if (half == 0) {
        #pragma unroll
        for (int i = 0; i < 26; i++) row[i] = f2bf(Z[i]);
        row[26] = f2bf(d0); row[27] = f2bf(d1); row[28] = f2bf(d2);
        row[29] = f2bf(dist); row[30] = f2bf(cx); row[31] = f2bf(cy);
    } else {
        row[0] = f2bf(cz); row[1] = f2bf(acr); row[2] = f2bf(1.f);
        #pragma unroll
        for (int i = 3; i < 32; i++) row[i] = 0;
        sKey[e_loc] = key;
    }
    v8s* dst = (v8s*)&sInp[e_loc * RS + half * 32];
    #pragma unroll
    for (int q = 0; q < 4; q++) dst[q] = ((v8s*)row)[q];
}

template<int STORE>
__global__ __launch_bounds__(256, 3) void edge_mfma(
    const float* __restrict__ z_l, const float* __restrict__ z_h,
    const int* __restrict__ src, const int* __restrict__ tgt,
    const int* __restrict__ sortedEdge,
    const float* __restrict__ We1, const float* __restrict__ be1,
    const float* __restrict__ We2, const float* __restrict__ be2,
    const float* __restrict__ Ww1, const float* __restrict__ bw1,
    const float* __restrict__ Ww2, const float* __restrict__ bw2,
    short* __restrict__ wmbuf, float* __restrict__ agg)
{
    __shared__ __align__(16) short sInp[128 * RS];   // features -> th -> wm
    __shared__ __align__(16) short sW1w[64 * RS];    // gate W1^T [n][k], bias@k=34
    __shared__ __align__(16) short sW1e[64 * RS];    // msg  W1^T [n][k], bias@k=34
    __shared__ __align__(16) short sWe2[32 * RS];    // We2^T [n][k]
    __shared__ int   sKey[128];
    __shared__ float sWw2[64], sBe2[32];
    __shared__ float sBw2;

    const int tid = threadIdx.x;

    // ---- stage weights once per block ----
    for (int idx = tid; idx < 64 * 64; idx += 256) {
        int n = idx & 63, k = idx >> 6;
        float vw = (k < EDGE_IN) ? Ww1[k * HID + n] : (k == EDGE_IN ? bw1[n] : 0.f);
        float ve = (k < EDGE_IN) ? We1[k * HID + n] : (k == EDGE_IN ? be1[n] : 0.f);
        sW1w[n * RS + k] = f2bf(vw);
        sW1e[n * RS + k] = f2bf(ve);
    }
    for (int idx = tid; idx < 32 * 64; idx += 256) {
        int n = idx & 31, k = idx >> 5;
        sWe2[n * RS + k] = f2bf(We2[k * MSG_DIM + n]);
    }
    if (tid < 64) sWw2[tid] = Ww2[tid];
    if (tid < 32) sBe2[tid] = be2[tid];
    if (tid == 0) sBw2 = bw2[0];

    const int e_loc = tid >> 1, half = tid & 1;
    const int lane = tid & 63, wv = tid >> 6;
    const int quad = lane >> 4, c = lane & 15;
    const int rbase = wv * 32;
    const int gidBase = blockIdx.x * (TPB_T * 128);

    // ---- prefetch preamble (contiguous tiles) ----
    #define GID_OF(i) (gidBase + (i) * 128 + e_loc)
    int egA = sortedEdge[GID_OF(0)];
    int sA = src[egA], tA = tgt[egA];
    float Z0[26];
    load_z(z_l, z_h, egA / E_CNT, sA, tA, Z0);
    int egB = sortedEdge[GID_OF(1)];
    int sB = src[egB], tB = tgt[egB];
    int egC = sortedEdge[GID_OF(2)];

    __syncthreads();   // weights visible; the ONLY barrier

    write_tile(sInp, sKey, e_loc, half, Z0, (egA / E_CNT) * N_H + tA);

    // hoist tile-invariant gate-path operands into registers
    float be2v[2];
    be2v[0] = sBe2[c]; be2v[1] = sBe2[16 + c];
    const float bw2v = sBw2;
    float ww2r[4];
    v8s Bg[4][2];
    #pragma unroll
    for (int ni = 0; ni < 4; ni++) {
        ww2r[ni] = sWw2[ni * 16 + c];
        Bg[ni][0] = *(const v8s*)&sW1w[(ni * 16 + c) * RS + quad * 8];
        Bg[ni][1] = *(const v8s*)&sW1w[(ni * 16 + c) * RS + 32 + quad * 8];
    }

    for (int t = 0; t < TPB_T; t++) {
        // ---- prefetch future tiles ----
        float Zn[26];
        if (t + 1 < TPB_T) load_z(z_l, z_h, egB / E_CNT, sB, tB, Zn);
        int sC = 0, tC = 0;
        if (t + 2 < TPB_T) { sC = src[egC]; tC = tgt[egC]; }
        int egD = egC;
        if (t + 3 < TPB_T) egD = sortedEdge[GID_OF(t + 3)];

        // ---- compute tile t (wave-private rows) ----
        v8s A1[2][2];
        #pragma unroll
        for (int mi = 0; mi < 2; mi++)
            #pragma unroll
            for (int kk = 0; kk < 2; kk++)
                A1[mi][kk] = *(const v8s*)&sInp[(rbase + mi * 16 + c) * RS + kk * 32 + quad * 8];

        // gate path: tanh fused per-ni (no Cg array)
        float pg[2][4];
        #pragma unroll
        for (int mi = 0; mi < 2; mi++)
            #pragma unroll
            for (int r = 0; r < 4; r++) pg[mi][r] = 0.f;
        #pragma unroll
        for (int ni = 0; ni < 4; ni++) {
            #pragma unroll
            for (int mi = 0; mi < 2; mi++) {
                v4f acc = {0.f, 0.f, 0.f, 0.f};
                acc = __builtin_amdgcn_mfma_f32_16x16x32_bf16(A1[mi][0], Bg[ni][0], acc, 0, 0, 0);
                acc = __builtin_amdgcn_mfma_f32_16x16x32_bf16(A1[mi][1], Bg[ni][1], acc, 0, 0, 0);
                #pragma unroll
                for (int r = 0; r < 4; r++)
                    pg[mi][r] += fast_tanh(acc[r]) * ww2r[ni];
            }
        }
        #pragma unroll
        for (int mk = 1; mk < 16; mk <<= 1)
            #pragma unroll
            for (int mi = 0; mi < 2; mi++)
                #pragma unroll
                for (int r = 0; r < 4; r++)
                    pg[mi][r] += __shfl_xor(pg[mi][r], mk, 64);
        float wgt[2][4];
        #pragma unroll
        for (int mi = 0; mi < 2; mi++)
            #pragma unroll
            for (int r = 0; r < 4; r++)
                wgt[mi][r] = fast_sigmoid(pg[mi][r] + bw2v);

        // msg GEMM1 -> tanh -> th into sInp (wave-private)
        #pragma unroll
        for (int ni = 0; ni < 4; ni++) {
            v8s B0 = *(const v8s*)&sW1e[(ni * 16 + c) * RS + quad * 8];
            v8s B1 = *(const v8s*)&sW1e[(ni * 16 + c) * RS + 32 + quad * 8];
            #pragma unroll
            for (int mi = 0; mi < 2; mi++) {
                v4f acc = {0.f, 0.f, 0.f, 0.f};
                acc = __builtin_amdgcn_mfma_f32_16x16x32_bf16(A1[mi][0], B0, acc, 0, 0, 0);
                acc = __builtin_amdgcn_mfma_f32_16x16x32_bf16(A1[mi][1], B1, acc, 0, 0, 0);
                #pragma unroll
                for (int r = 0; r < 4; r++)
                    sInp[(rbase + mi * 16 + quad * 4 + r) * RS + ni * 16 + c] =
                        f2bf(fast_tanh(acc[r]));
            }
        }

        // GEMM2: m = th @ We2, gate, wm bf16 into sInp cols 0..31
        v8s A2[2][2];
        #pragma unroll
        for (int mi = 0; mi < 2; mi++)
            #pragma unroll
            for (int kk = 0; kk < 2; kk++)
                A2[mi][kk] = *(const v8s*)&sInp[(rbase + mi * 16 + c) * RS + kk * 32 + quad * 8];
        #pragma unroll
        for (int nj = 0; nj < 2; nj++) {
            v8s B0 = *(const v8s*)&sWe2[(nj * 16 + c) * RS + quad * 8];
            v8s B1 = *(const v8s*)&sWe2[(nj * 16 + c) * RS + 32 + quad * 8];
            #pragma unroll
            for (int mi = 0; mi < 2; mi++) {
                v4f acc = {0.f, 0.f, 0.f, 0.f};
                acc = __builtin_amdgcn_mfma_f32_16x16x32_bf16(A2[mi][0], B0, acc, 0, 0, 0);
                acc = __builtin_amdgcn_mfma_f32_16x16x32_bf16(A2[mi][1], B1, acc, 0, 0, 0);
                #pragma unroll
                for (int r = 0; r < 4; r++)
                    sInp[(rbase + mi * 16 + quad * 4 + r) * RS + nj * 16 + c] =
                        f2bf((acc[r] + be2v[nj]) * wgt[mi][r]);
            }
        }

        if (STORE == 1) {
            // contiguous coalesced store of wm rows at sorted position
            int e2 = lane >> 1, hf2 = lane & 1;
            int lrow = rbase + e2;
            const v8s* p = (const v8s*)&sInp[lrow * RS + hf2 * 16];
            v8s h0 = p[0], h1 = p[1];
            short* dst = wmbuf + ((size_t)(gidBase + t * 128 + lrow) * MSG_DIM + hf2 * 16);
            *(v8s*)dst = h0;
            *(v8s*)(dst + 8) = h1;
        } else {
            // fallback: segmented suffix-sum + run-head atomics
            int e = lane & 31, hf = lane >> 5;
            int key = sKey[rbase + e];
            int base = (rbase + e) * RS + hf * 16;
            v8s h0 = *(const v8s*)&sInp[base];
            v8s h1 = *(const v8s*)&sInp[base + 8];
            float v[16];
            #pragma unroll
            for (int j = 0; j < 8; j++) { v[j] = bf2f(h0[j]); v[8 + j] = bf2f(h1[j]); }
            #pragma unroll
            for (int k2 = 0; k2 < 5; k2++) {
                int off = 1 << k2;
                int ko = __shfl_down(key, off, 64);
                bool take = (e + off < 32) && (ko == key);
                #pragma unroll
                for (int j = 0; j < 16; j++) {
                    float o = __shfl_down(v[j], off, 64);
                    if (take) v[j] += o;
                }
            }
            int keyup = __shfl_up(key, 1, 64);
            if (e == 0 || keyup != key) {
                float* dst = agg + (size_t)key * MSG_DIM + hf * 16;
                #pragma unroll
                for (int j = 0; j < 16; j++) atomicAdd(dst + j, v[j]);
            }
        }

        // ---- stage tile t+1 (wave-private, no barrier) ----
        if (t + 1 < TPB_T)
            write_tile(sInp, sKey, e_loc, half, Zn, (egB / E_CNT) * N_H + tB);

        egB = egC; sB = sC; tB = tC; egC = egD;
    }
    #undef GID_OF
}

// ---------------- node kernel ----------------
// FROMWM=1: block owns 256 consecutive keys; their wm rows are one contiguous
// range [start[base], start[base+nkey]). Cooperative coalesced row streaming,
// binary-search key, LDS-atomic accumulate, then per-thread MLP.
#define AS 33   // sAcc row stride (pad to break bank alignment)
template<int FROMWM>
__global__ __launch_bounds__(256) void node_kernel(
    const float* __restrict__ z_h,
    const short* __restrict__ wmbuf, const float* __restrict__ agg,
    const int* __restrict__ start,
    const float* __restrict__ Wn1, const float* __restrict__ bn1,
    const float* __restrict__ Wn2, const float* __restrict__ bn2,
    float* __restrict__ out)
{
    __shared__ float sWn1[NODE_IN * HID];
    __shared__ float sWn2[HID * F_DIM];
    __shared__ float sbn1[HID], sbn2[F_DIM];
    __shared__ float sAcc[256 * AS];
    __shared__ int   sStart[257];

    const int tid = threadIdx.x;
    const int base = blockIdx.x * 256;
    const int nkey = min(256, KTOT - base);

    for (int i = tid; i < NODE_IN * HID; i += 256) sWn1[i] = Wn1[i];
    for (int i = tid; i < HID * F_DIM; i += 256) sWn2[i] = Wn2[i];
    if (tid < HID) sbn1[tid] = bn1[tid];
    if (tid < F_DIM) sbn2[tid] = bn2[tid];

    if (FROMWM) {
        // FIX(R7 crash): cover index nkey (inclusive) — stride loop, not tid test
        for (int i = tid; i <= nkey; i += 256) sStart[i] = start[base + i];
        // FIX(R7): zero ALL of sAcc (33 strides of 256), not just the first 8
        for (int i = tid; i < 256 * AS; i += 256) sAcc[i] = 0.f;
    }
    __syncthreads();

    float acc[MSG_DIM];

    if (FROMWM) {
        int r0 = sStart[0], r1 = sStart[nkey];
        for (int r = r0 + tid; r < r1; r += 256) {
            // binary search: key j with sStart[j] <= r < sStart[j+1]
            int lo = 0, hi = nkey;
            while (hi - lo > 1) {
                int mid = (lo + hi) >> 1;
                if (sStart[mid] <= r) lo = mid; else hi = mid;
            }
            const v8s* p = (const v8s*)(wmbuf + (size_t)r * MSG_DIM);
            #pragma unroll
            for (int q = 0; q < 4; q++) {
                v8s h = p[q];
                #pragma unroll
                for (int j = 0; j < 8; j++)
                    atomicAdd(&sAcc[lo * AS + q * 8 + j], bf2f(h[j]));
            }
        }
        __syncthreads();
        if (tid >= nkey) return;
        #pragma unroll
        for (int j = 0; j < MSG_DIM; j++) acc[j] = sAcc[tid * AS + j];
    } else {
        if (tid >= nkey) return;
        #pragma unroll
        for (int j = 0; j < MSG_DIM; j++) acc[j] = agg[(size_t)(base + tid) * MSG_DIM + j];
    }

    int key = base + tid;
    float zt[F_DIM];
    #pragma unroll
    for (int i = 0; i < F_DIM; i++) zt[i] = z_h[(size_t)key * F_DIM + i];

    float hid[HID];
    #pragma unroll
    for (int h = 0; h < HID; h++) hid[h] = sbn1[h];
    #pragma unroll
    for (int k = 0; k < NODE_IN; k++) {
        float x = (k < F_DIM) ? zt[k] : acc[k - F_DIM];
        #pragma unroll
        for (int h = 0; h < HID; h++) hid[h] = fmaf(x, sWn1[k * HID + h], hid[h]);
    }
    float o[F_DIM];
    #pragma unroll
    for (int j = 0; j < F_DIM; j++) o[j] = sbn2[j];
    #pragma unroll
    for (int h = 0; h < HID; h++) {
        float th = fast_tanh(hid[h]);
        #pragma unroll
        for (int j = 0; j < F_DIM; j++) o[j] = fmaf(th, sWn2[h * F_DIM + j], o[j]);
    }
    #pragma unroll
    for (int j = 0; j < F_DIM; j++) out[(size_t)key * F_DIM + j] = o[j];
}

extern "C" void kernel_launch(void* const* d_in, const int* in_sizes, int n_in,
                              void* d_out, int out_size, void* d_ws, size_t ws_size,
                              hipStream_t stream)
{
    const float* z_l = (const float*)d_in[0];
    const float* z_h = (const float*)d_in[1];
    const int*   src = (const int*)d_in[2];
    const int*   tgt = (const int*)d_in[3];
    const float* We1 = (const float*)d_in[4];  const float* be1 = (const float*)d_in[5];
    const float* We2 = (const float*)d_in[6];  const float* be2 = (const float*)d_in[7];
    const float* Ww1 = (const float*)d_in[8];  const float* bw1 = (const float*)d_in[9];
    const float* Ww2 = (const float*)d_in[10]; const float* bw2 = (const float*)d_in[11];
    const float* Wn1 = (const float*)d_in[12]; const float* bn1 = (const float*)d_in[13];
    const float* Wn2 = (const float*)d_in[14]; const float* bn2 = (const float*)d_in[15];
    float* out = (float*)d_out;

    int* start      = (int*)d_ws;              // SCAN_N
    int* cursor     = start + SCAN_N;          // KTOT
    int* blkSums    = cursor + KTOT;           // 1024
    int* blkOff     = blkSums + 1024;          // 1024
    int* sortedEdge = blkOff + 1024;           // NE_TOT
    size_t csrBytes = ((size_t)SCAN_N + KTOT + 2048 + NE_TOT) * sizeof(int);
    size_t bigOff   = (csrBytes + 255) & ~(size_t)255;

    const int nScanBlk = (SCAN_N + 1023) / 1024;
    const int nodeGrid = (KTOT + 255) / 256;

    // CSR build (shared by both paths)
    hipMemsetAsync(start, 0, SCAN_N * sizeof(int), stream);
    hist_kernel<<<NE_TOT / 256, 256, 0, stream>>>(tgt, start);
    scan_blocks<<<nScanBlk, 256, 0, stream>>>(start, blkSums, SCAN_N);
    scan_top<<<1, 512, 0, stream>>>(blkSums, blkOff, nScanBlk);
    scan_add<<<nScanBlk, 256, 0, stream>>>(start, blkOff, cursor, SCAN_N, KTOT);
    fill_kernel<<<NE_TOT / 256, 256, 0, stream>>>(tgt, cursor, sortedEdge);

    size_t needWm = bigOff + (size_t)NE_TOT * MSG_DIM * sizeof(short);   // ~221 MB

    if (ws_size >= needWm) {
        short* wmbuf = (short*)((char*)d_ws + bigOff);
        edge_mfma<1><<<GRID_E, 256, 0, stream>>>(
            z_l, z_h, src, tgt, sortedEdge,
            We1, be1, We2, be2, Ww1, bw1, Ww2, bw2, wmbuf, (float*)nullptr);
        node_kernel<1><<<nodeGrid, 256, 0, stream>>>(
            z_h, wmbuf, (const float*)nullptr, start, Wn1, bn1, Wn2, bn2, out);
    } else {
        float* agg = (float*)((char*)d_ws + bigOff);   // 51.2 MB (fits per R3)
        hipMemsetAsync(agg, 0, (size_t)KTOT * MSG_DIM * sizeof(float), stream);
        edge_mfma<0><<<GRID_E, 256, 0, stream>>>(
            z_l, z_h, src, tgt, sortedEdge,
            We1, be1, We2, be2, Ww1, bw1, Ww2, bw2, (short*)nullptr, agg);
        node_kernel<0><<<nodeGrid, 256, 0, stream>>>(
            z_h, (const short*)nullptr, agg, start, Wn1, bn1, Wn2, bn2, out);
    }
}

// Round 9
// 616.579 us; speedup vs baseline: 2.5278x; 2.5278x over previous
//
#include <hip/hip_runtime.h>
#include <hip/hip_bf16.h>

#define F_DIM   13
#define EDGE_IN 34
#define MSG_DIM 32
#define HID     64
#define NODE_IN 45
#define N_L     20000
#define N_H     100000
#define E_CNT   800000
#define B_CNT   4
#define KTOT    (B_CNT * N_H)      // 400000
#define NE_TOT  (B_CNT * E_CNT)    // 3200000
#define SCAN_N  (KTOT + 1)

#define RS       72                // LDS row stride in halfwords (144 B)
#define GRID_E   2500
#define TPB_T    10                // tiles/block; 2500*10*128 = 3.2M edges

typedef short v8s __attribute__((ext_vector_type(8)));
typedef float v4f __attribute__((ext_vector_type(4)));

// tanh = 1 - 2/(exp2(2log2e*x)+1); rcp(inf)=0 -> saturates to +/-1, no clamps
__device__ __forceinline__ float fast_tanh(float x) {
    float t = __builtin_amdgcn_exp2f(x * 2.885390081777927f);
    return fmaf(-2.f, __builtin_amdgcn_rcpf(t + 1.f), 1.f);
}
__device__ __forceinline__ float fast_sigmoid(float x) {
    float t = __builtin_amdgcn_exp2f(-x * 1.4426950408889634f);
    return __builtin_amdgcn_rcpf(1.f + t);
}
__device__ __forceinline__ short f2bf(float f) {     // round-half-up: 2 instr
    union { float f; unsigned u; } x; x.f = f;
    return (short)((x.u + 0x8000u) >> 16);
}
__device__ __forceinline__ float bf2f(short s) {
    union { unsigned u; float f; } x;
    x.u = ((unsigned)(unsigned short)s) << 16;
    return x.f;
}

// ---------------- CSR build: rank trick (one atomic pass) ----------------

// rank[e] = old count; arr[key+1] += 1 (arr pre-zeroed)
__global__ __launch_bounds__(256) void rank_kernel(const int* __restrict__ tgt,
                                                   int* __restrict__ arr,
                                                   unsigned short* __restrict__ rank) {
    int gid = blockIdx.x * 256 + threadIdx.x;
    int b = gid / E_CNT;
    int key = b * N_H + tgt[gid];
    rank[gid] = (unsigned short)atomicAdd(&arr[key + 1], 1);
}

__global__ __launch_bounds__(256) void scan_blocks(int* __restrict__ data,
                                                   int* __restrict__ blkSums, int n) {
    __shared__ int sh[256];
    int base = blockIdx.x * 1024 + threadIdx.x * 4;
    int v0 = 0, v1 = 0, v2 = 0, v3 = 0;
    if (base + 0 < n) v0 = data[base + 0];
    if (base + 1 < n) v1 = data[base + 1];
    if (base + 2 < n) v2 = data[base + 2];
    if (base + 3 < n) v3 = data[base + 3];
    v1 += v0; v2 += v1; v3 += v2;
    int val = v3;
    sh[threadIdx.x] = val;
    __syncthreads();
    for (int off = 1; off < 256; off <<= 1) {
        int t = (threadIdx.x >= off) ? sh[threadIdx.x - off] : 0;
        __syncthreads();
        sh[threadIdx.x] += t;
        __syncthreads();
    }
    int excl = sh[threadIdx.x] - val;
    if (base + 0 < n) data[base + 0] = v0 + excl;
    if (base + 1 < n) data[base + 1] = v1 + excl;
    if (base + 2 < n) data[base + 2] = v2 + excl;
    if (base + 3 < n) data[base + 3] = v3 + excl;
    if (threadIdx.x == 255) blkSums[blockIdx.x] = sh[255];
}

__global__ __launch_bounds__(512) void scan_top(const int* __restrict__ blkSums,
                                                int* __restrict__ blkOff, int nb) {
    __shared__ int sh[512];
    int v = (threadIdx.x < nb) ? blkSums[threadIdx.x] : 0;
    sh[threadIdx.x] = v;
    __syncthreads();
    for (int off = 1; off < 512; off <<= 1) {
        int t = (threadIdx.x >= off) ? sh[threadIdx.x - off] : 0;
        __syncthreads();
        sh[threadIdx.x] += t;
        __syncthreads();
    }
    blkOff[threadIdx.x] = sh[threadIdx.x] - v;
}

__global__ __launch_bounds__(256) void scan_add(int* __restrict__ data,
                                                const int* __restrict__ blkOff, int n) {
    int base = blockIdx.x * 1024 + threadIdx.x * 4;
    int off = blkOff[blockIdx.x];
    #pragma unroll
    for (int j = 0; j < 4; j++) {
        int i = base + j;
        if (i < n) data[i] += off;
    }
}

// sortedEdge[start[key] + rank[e]] = e  (no atomics)
__global__ __launch_bounds__(256) void pos_kernel(const int* __restrict__ tgt,
                                                  const int* __restrict__ start,
                                                  const unsigned short* __restrict__ rank,
                                                  int* __restrict__ sortedEdge) {
    int gid = blockIdx.x * 256 + threadIdx.x;
    int b = gid / E_CNT;
    int key = b * N_H + tgt[gid];
    sortedEdge[start[key] + (int)rank[gid]] = gid;
}

// ---------------- persistent MFMA edge kernel (validated R8) ----------------

__device__ __forceinline__ void load_z(const float* __restrict__ z_l,
                                       const float* __restrict__ z_h,
                                       int b, int s, int t, float* Z) {
    const float* zs = z_l + ((size_t)b * N_L + s) * F_DIM;
    const float* zt = z_h + ((size_t)b * N_H + t) * F_DIM;
    #pragma unroll
    for (int i = 0; i < F_DIM; i++) Z[i] = zs[i];
    #pragma unroll
    for (int i = 0; i < F_DIM; i++) Z[13 + i] = zt[i];
}

__device__ __forceinline__ void write_tile(short* __restrict__ sInp,
                                           int* __restrict__ sKey,
                                           int e_loc, int half,
                                           const float* __restrict__ Z, int key) {
    float d0 = Z[0] - Z[13], d1 = Z[1] - Z[14], d2 = Z[2] - Z[15];
    float dist = d0 * d0 + d1 * d1 + d2 * d2;
    float ax = Z[3], ay = Z[4], az = Z[5];
    float bx = Z[16], by = Z[17], bz = Z[18];
    float cx = ay * bz - az * by;
    float cy = az * bx - ax * bz;
    float cz = ax * by - ay * bx;
    float acr = sqrtf(cx * cx + cy * cy + cz * cz);

    short row[32];
    if (half == 0) {
        #pragma unroll
        for (int i = 0; i < 26; i++) row[i] = f2bf(Z[i]);
        row[26] = f2bf(d0); row[27] = f2bf(d1); row[28] = f2bf(d2);
        row[29] = f2bf(dist); row[30] = f2bf(cx); row[31] = f2bf(cy);
    } else {
        row[0] = f2bf(cz); row[1] = f2bf(acr); row[2] = f2bf(1.f);
        #pragma unroll
        for (int i = 3; i < 32; i++) row[i] = 0;
        sKey[e_loc] = key;
    }
    v8s* dst = (v8s*)&sInp[e_loc * RS + half * 32];
    #pragma unroll
    for (int q = 0; q < 4; q++) dst[q] = ((v8s*)row)[q];
}

template<int STORE>
__global__ __launch_bounds__(256, 3) void edge_mfma(
    const float* __restrict__ z_l, const float* __restrict__ z_h,
    const int* __restrict__ src, const int* __restrict__ tgt,
    const int* __restrict__ sortedEdge,
    const float* __restrict__ We1, const float* __restrict__ be1,
    const float* __restrict__ We2, const float* __restrict__ be2,
    const float* __restrict__ Ww1, const float* __restrict__ bw1,
    const float* __restrict__ Ww2, const float* __restrict__ bw2,
    short* __restrict__ wmbuf, float* __restrict__ agg)
{
    __shared__ __align__(16) short sInp[128 * RS];   // features -> th -> wm
    __shared__ __align__(16) short sW1w[64 * RS];    // gate W1^T [n][k], bias@k=34
    __shared__ __align__(16) short sW1e[64 * RS];    // msg  W1^T [n][k], bias@k=34
    __shared__ __align__(16) short sWe2[32 * RS];    // We2^T [n][k]
    __shared__ int   sKey[128];
    __shared__ float sWw2[64], sBe2[32];
    __shared__ float sBw2;

    const int tid = threadIdx.x;

    // ---- stage weights once per block ----
    for (int idx = tid; idx < 64 * 64; idx += 256) {
        int n = idx & 63, k = idx >> 6;
        float vw = (k < EDGE_IN) ? Ww1[k * HID + n] : (k == EDGE_IN ? bw1[n] : 0.f);
        float ve = (k < EDGE_IN) ? We1[k * HID + n] : (k == EDGE_IN ? be1[n] : 0.f);
        sW1w[n * RS + k] = f2bf(vw);
        sW1e[n * RS + k] = f2bf(ve);
    }
    for (int idx = tid; idx < 32 * 64; idx += 256) {
        int n = idx & 31, k = idx >> 5;
        sWe2[n * RS + k] = f2bf(We2[k * MSG_DIM + n]);
    }
    if (tid < 64) sWw2[tid] = Ww2[tid];
    if (tid < 32) sBe2[tid] = be2[tid];
    if (tid == 0) sBw2 = bw2[0];

    const int e_loc = tid >> 1, half = tid & 1;
    const int lane = tid & 63, wv = tid >> 6;
    const int quad = lane >> 4, c = lane & 15;
    const int rbase = wv * 32;
    const int gidBase = blockIdx.x * (TPB_T * 128);

    // ---- prefetch preamble (contiguous tiles) ----
    #define GID_OF(i) (gidBase + (i) * 128 + e_loc)
    int egA = sortedEdge[GID_OF(0)];
    int sA = src[egA], tA = tgt[egA];
    float Z0[26];
    load_z(z_l, z_h, egA / E_CNT, sA, tA, Z0);
    int egB = sortedEdge[GID_OF(1)];
    int sB = src[egB], tB = tgt[egB];
    int egC = sortedEdge[GID_OF(2)];

    __syncthreads();   // weights visible; the ONLY barrier

    write_tile(sInp, sKey, e_loc, half, Z0, (egA / E_CNT) * N_H + tA);

    // hoist tile-invariant gate-path operands into registers
    float be2v[2];
    be2v[0] = sBe2[c]; be2v[1] = sBe2[16 + c];
    const float bw2v = sBw2;
    float ww2r[4];
    v8s Bg[4][2];
    #pragma unroll
    for (int ni = 0; ni < 4; ni++) {
        ww2r[ni] = sWw2[ni * 16 + c];
        Bg[ni][0] = *(const v8s*)&sW1w[(ni * 16 + c) * RS + quad * 8];
        Bg[ni][1] = *(const v8s*)&sW1w[(ni * 16 + c) * RS + 32 + quad * 8];
    }

    for (int t = 0; t < TPB_T; t++) {
        // ---- prefetch future tiles ----
        float Zn[26];
        if (t + 1 < TPB_T) load_z(z_l, z_h, egB / E_CNT, sB, tB, Zn);
        int sC = 0, tC = 0;
        if (t + 2 < TPB_T) { sC = src[egC]; tC = tgt[egC]; }
        int egD = egC;
        if (t + 3 < TPB_T) egD = sortedEdge[GID_OF(t + 3)];

        // ---- compute tile t (wave-private rows) ----
        v8s A1[2][2];
        #pragma unroll
        for (int mi = 0; mi < 2; mi++)
            #pragma unroll
            for (int kk = 0; kk < 2; kk++)
                A1[mi][kk] = *(const v8s*)&sInp[(rbase + mi * 16 + c) * RS + kk * 32 + quad * 8];

        // gate path: tanh fused per-ni
        float pg[2][4];
        #pragma unroll
        for (int mi = 0; mi < 2; mi++)
            #pragma unroll
            for (int r = 0; r < 4; r++) pg[mi][r] = 0.f;
        #pragma unroll
        for (int ni = 0; ni < 4; ni++) {
            #pragma unroll
            for (int mi = 0; mi < 2; mi++) {
                v4f acc = {0.f, 0.f, 0.f, 0.f};
                acc = __builtin_amdgcn_mfma_f32_16x16x32_bf16(A1[mi][0], Bg[ni][0], acc, 0, 0, 0);
                acc = __builtin_amdgcn_mfma_f32_16x16x32_bf16(A1[mi][1], Bg[ni][1], acc, 0, 0, 0);
                #pragma unroll
                for (int r = 0; r < 4; r++)
                    pg[mi][r] += fast_tanh(acc[r]) * ww2r[ni];
            }
        }
        #pragma unroll
        for (int mk = 1; mk < 16; mk <<= 1)
            #pragma unroll
            for (int mi = 0; mi < 2; mi++)
                #pragma unroll
                for (int r = 0; r < 4; r++)
                    pg[mi][r] += __shfl_xor(pg[mi][r], mk, 64);
        float wgt[2][4];
        #pragma unroll
        for (int mi = 0; mi < 2; mi++)
            #pragma unroll
            for (int r = 0; r < 4; r++)
                wgt[mi][r] = fast_sigmoid(pg[mi][r] + bw2v);

        // msg GEMM1 -> tanh -> th into sInp (wave-private)
        #pragma unroll
        for (int ni = 0; ni < 4; ni++) {
            v8s B0 = *(const v8s*)&sW1e[(ni * 16 + c) * RS + quad * 8];
            v8s B1 = *(const v8s*)&sW1e[(ni * 16 + c) * RS + 32 + quad * 8];
            #pragma unroll
            for (int mi = 0; mi < 2; mi++) {
                v4f acc = {0.f, 0.f, 0.f, 0.f};
                acc = __builtin_amdgcn_mfma_f32_16x16x32_bf16(A1[mi][0], B0, acc, 0, 0, 0);
                acc = __builtin_amdgcn_mfma_f32_16x16x32_bf16(A1[mi][1], B1, acc, 0, 0, 0);
                #pragma unroll
                for (int r = 0; r < 4; r++)
                    sInp[(rbase + mi * 16 + quad * 4 + r) * RS + ni * 16 + c] =
                        f2bf(fast_tanh(acc[r]));
            }
        }

        // GEMM2: m = th @ We2, gate, wm bf16 into sInp cols 0..31
        v8s A2[2][2];
        #pragma unroll
        for (int mi = 0; mi < 2; mi++)
            #pragma unroll
            for (int kk = 0; kk < 2; kk++)
                A2[mi][kk] = *(const v8s*)&sInp[(rbase + mi * 16 + c) * RS + kk * 32 + quad * 8];
        #pragma unroll
        for (int nj = 0; nj < 2; nj++) {
            v8s B0 = *(const v8s*)&sWe2[(nj * 16 + c) * RS + quad * 8];
            v8s B1 = *(const v8s*)&sWe2[(nj * 16 + c) * RS + 32 + quad * 8];
            #pragma unroll
            for (int mi = 0; mi < 2; mi++) {
                v4f acc = {0.f, 0.f, 0.f, 0.f};
                acc = __builtin_amdgcn_mfma_f32_16x16x32_bf16(A2[mi][0], B0, acc, 0, 0, 0);
                acc = __builtin_amdgcn_mfma_f32_16x16x32_bf16(A2[mi][1], B1, acc, 0, 0, 0);
                #pragma unroll
                for (int r = 0; r < 4; r++)
                    sInp[(rbase + mi * 16 + quad * 4 + r) * RS + nj * 16 + c] =
                        f2bf((acc[r] + be2v[nj]) * wgt[mi][r]);
            }
        }

        if (STORE == 1) {
            // contiguous coalesced store of wm rows at sorted position
            int e2 = lane >> 1, hf2 = lane & 1;
            int lrow = rbase + e2;
            const v8s* p = (const v8s*)&sInp[lrow * RS + hf2 * 16];
            v8s h0 = p[0], h1 = p[1];
            short* dst = wmbuf + ((size_t)(gidBase + t * 128 + lrow) * MSG_DIM + hf2 * 16);
            *(v8s*)dst = h0;
            *(v8s*)(dst + 8) = h1;
        } else {
            // fallback: segmented suffix-sum + run-head atomics
            int e = lane & 31, hf = lane >> 5;
            int key = sKey[rbase + e];
            int base = (rbase + e) * RS + hf * 16;
            v8s h0 = *(const v8s*)&sInp[base];
            v8s h1 = *(const v8s*)&sInp[base + 8];
            float v[16];
            #pragma unroll
            for (int j = 0; j < 8; j++) { v[j] = bf2f(h0[j]); v[8 + j] = bf2f(h1[j]); }
            #pragma unroll
            for (int k2 = 0; k2 < 5; k2++) {
                int off = 1 << k2;
                int ko = __shfl_down(key, off, 64);
                bool take = (e + off < 32) && (ko == key);
                #pragma unroll
                for (int j = 0; j < 16; j++) {
                    float o = __shfl_down(v[j], off, 64);
                    if (take) v[j] += o;
                }
            }
            int keyup = __shfl_up(key, 1, 64);
            if (e == 0 || keyup != key) {
                float* dst = agg + (size_t)key * MSG_DIM + hf * 16;
                #pragma unroll
                for (int j = 0; j < 16; j++) atomicAdd(dst + j, v[j]);
            }
        }

        // ---- stage tile t+1 (wave-private, no barrier) ----
        if (t + 1 < TPB_T)
            write_tile(sInp, sKey, e_loc, half, Zn, (egB / E_CNT) * N_H + tB);

        egB = egC; sB = sC; tB = tC; egC = egD;
    }
    #undef GID_OF
}

// ---------------- node kernel (reverted to proven R6 shape) ----------------
// FROMWM=1: acc = sum of bf16 wm rows [start[key], start[key+1]); else read agg.
template<int FROMWM>
__global__ __launch_bounds__(256) void node_kernel(
    const float* __restrict__ z_h,
    const short* __restrict__ wmbuf, const float* __restrict__ agg,
    const int* __restrict__ start,
    const float* __restrict__ Wn1, const float* __restrict__ bn1,
    const float* __restrict__ Wn2, const float* __restrict__ bn2,
    float* __restrict__ out)
{
    __shared__ float sWn1[NODE_IN * HID];
    __shared__ float sWn2[HID * F_DIM];
    __shared__ float sbn1[HID], sbn2[F_DIM];
    for (int i = threadIdx.x; i < NODE_IN * HID; i += 256) sWn1[i] = Wn1[i];
    for (int i = threadIdx.x; i < HID * F_DIM; i += 256) sWn2[i] = Wn2[i];
    if (threadIdx.x < HID) sbn1[threadIdx.x] = bn1[threadIdx.x];
    if (threadIdx.x < F_DIM) sbn2[threadIdx.x] = bn2[threadIdx.x];
    __syncthreads();

    int key = blockIdx.x * 256 + threadIdx.x;
    if (key >= KTOT) return;

    float zt[F_DIM];
    #pragma unroll
    for (int i = 0; i < F_DIM; i++) zt[i] = z_h[(size_t)key * F_DIM + i];

    float acc[MSG_DIM];
    if (FROMWM) {
        #pragma unroll
        for (int j = 0; j < MSG_DIM; j++) acc[j] = 0.f;
        int i0 = start[key], i1 = start[key + 1];
        for (int i = i0; i < i1; i++) {
            const v8s* p = (const v8s*)(wmbuf + (size_t)i * MSG_DIM);
            #pragma unroll
            for (int q = 0; q < 4; q++) {
                v8s h = p[q];
                #pragma unroll
                for (int j = 0; j < 8; j++) acc[q * 8 + j] += bf2f(h[j]);
            }
        }
    } else {
        #pragma unroll
        for (int j = 0; j < MSG_DIM; j++) acc[j] = agg[(size_t)key * MSG_DIM + j];
    }

    float hid[HID];
    #pragma unroll
    for (int h = 0; h < HID; h++) hid[h] = sbn1[h];
    #pragma unroll
    for (int k = 0; k < NODE_IN; k++) {
        float x = (k < F_DIM) ? zt[k] : acc[k - F_DIM];
        #pragma unroll
        for (int h = 0; h < HID; h++) hid[h] = fmaf(x, sWn1[k * HID + h], hid[h]);
    }
    float o[F_DIM];
    #pragma unroll
    for (int j = 0; j < F_DIM; j++) o[j] = sbn2[j];
    #pragma unroll
    for (int h = 0; h < HID; h++) {
        float th = fast_tanh(hid[h]);
        #pragma unroll
        for (int j = 0; j < F_DIM; j++) o[j] = fmaf(th, sWn2[h * F_DIM + j], o[j]);
    }
    #pragma unroll
    for (int j = 0; j < F_DIM; j++) out[(size_t)key * F_DIM + j] = o[j];
}

extern "C" void kernel_launch(void* const* d_in, const int* in_sizes, int n_in,
                              void* d_out, int out_size, void* d_ws, size_t ws_size,
                              hipStream_t stream)
{
    const float* z_l = (const float*)d_in[0];
    const float* z_h = (const float*)d_in[1];
    const int*   src = (const int*)d_in[2];
    const int*   tgt = (const int*)d_in[3];
    const float* We1 = (const float*)d_in[4];  const float* be1 = (const float*)d_in[5];
    const float* We2 = (const float*)d_in[6];  const float* be2 = (const float*)d_in[7];
    const float* Ww1 = (const float*)d_in[8];  const float* bw1 = (const float*)d_in[9];
    const float* Ww2 = (const float*)d_in[10]; const float* bw2 = (const float*)d_in[11];
    const float* Wn1 = (const float*)d_in[12]; const float* bn1 = (const float*)d_in[13];
    const float* Wn2 = (const float*)d_in[14]; const float* bn2 = (const float*)d_in[15];
    float* out = (float*)d_out;

    // workspace layout (cursor removed; rank aliases the big buffer)
    int* start      = (int*)d_ws;              // SCAN_N
    int* blkSums    = start + SCAN_N;          // 1024
    int* blkOff     = blkSums + 1024;          // 1024
    int* sortedEdge = blkOff + 1024;           // NE_TOT
    size_t csrBytes = ((size_t)SCAN_N + 2048 + NE_TOT) * sizeof(int);
    size_t bigOff   = (csrBytes + 255) & ~(size_t)255;
    unsigned short* rank = (unsigned short*)((char*)d_ws + bigOff);  // NE_TOT ushort,
                                                                     // dead after pos_kernel

    const int nScanBlk = (SCAN_N + 1023) / 1024;
    const int nodeGrid = (KTOT + 255) / 256;

    // CSR build: one atomic pass (rank), scan, plain scatter (pos)
    hipMemsetAsync(start, 0, SCAN_N * sizeof(int), stream);
    rank_kernel<<<NE_TOT / 256, 256, 0, stream>>>(tgt, start, rank);
    scan_blocks<<<nScanBlk, 256, 0, stream>>>(start, blkSums, SCAN_N);
    scan_top<<<1, 512, 0, stream>>>(blkSums, blkOff, nScanBlk);
    scan_add<<<nScanBlk, 256, 0, stream>>>(start, blkOff, SCAN_N);
    pos_kernel<<<NE_TOT / 256, 256, 0, stream>>>(tgt, start, rank, sortedEdge);

    size_t needWm = bigOff + (size_t)NE_TOT * MSG_DIM * sizeof(short);   // ~219 MB

    if (ws_size >= needWm) {
        short* wmbuf = (short*)((char*)d_ws + bigOff);   // overwrites rank (dead)
        edge_mfma<1><<<GRID_E, 256, 0, stream>>>(
            z_l, z_h, src, tgt, sortedEdge,
            We1, be1, We2, be2, Ww1, bw1, Ww2, bw2, wmbuf, (float*)nullptr);
        node_kernel<1><<<nodeGrid, 256, 0, stream>>>(
            z_h, wmbuf, (const float*)nullptr, start, Wn1, bn1, Wn2, bn2, out);
    } else {
        // fallback: agg after the rank region (rank dead by then)
        float* agg = (float*)((char*)d_ws + bigOff);
        hipMemsetAsync(agg, 0, (size_t)KTOT * MSG_DIM * sizeof(float), stream);
        edge_mfma<0><<<GRID_E, 256, 0, stream>>>(
            z_l, z_h, src, tgt, sortedEdge,
            We1, be1, We2, be2, Ww1, bw1, Ww2, bw2, (short*)nullptr, agg);
        node_kernel<0><<<nodeGrid, 256, 0, stream>>>(
            z_h, (const short*)nullptr, agg, start, Wn1, bn1, Wn2, bn2, out);
    }
}